// Round 6
// baseline (1023.502 us; speedup 1.0000x reference)
//
#include <hip/hip_runtime.h>
#include <stdint.h>

#define Bb 8
#define Tt 2048
#define Cc 512

typedef __attribute__((ext_vector_type(8))) short short8;
typedef __attribute__((ext_vector_type(4))) float f32x4;

__device__ __forceinline__ float b2f(short s) {
  unsigned int x = ((unsigned int)(unsigned short)s) << 16;
  return __builtin_bit_cast(float, x);
}
__device__ __forceinline__ short f2b(float f) {
  unsigned int x = __builtin_bit_cast(unsigned int, f);
  x += 0x7fffu + ((x >> 16) & 1u);   // round-to-nearest-even
  return (short)(x >> 16);
}

// Async global->LDS 16B copy. LDS dest is wave-uniform base + lane*16.
__device__ __forceinline__ void async_copy16(const short* g, short* l) {
  __builtin_amdgcn_global_load_lds(
      (const __attribute__((address_space(1))) unsigned int*)g,
      (__attribute__((address_space(3))) unsigned int*)l,
      16, 0, 0);
}

// ---------------------------------------------------------------------------
// GEMM: C[m,n] = epilogue( sum_k A[m,k] * B[n,k] )   (B row-major N x K, bf16)
// MODE 0: A fp32 (manual convert-stage), C bf16, +bias[n]     (pointwise)
// MODE 3: A bf16 async,                  C fp32, +bias+resid  (out proj)
// 128x128 tile, BK=64, 4 waves 2x2, wave tile 64x64 via 4x4 MFMA 16x16x32.
// LDS: m-major row-XOR swizzle, chunk (m,kc) at m*8 + (kc^(m&7)). Verified
// conflict-free (SQ_LDS_BANK_CONFLICT=0, round 5).
// ---------------------------------------------------------------------------
template<int MODE>
__global__ __launch_bounds__(256, 4)
void gemm_bt(const void* __restrict__ Av, const void* __restrict__ Bv,
             void* __restrict__ Cv, const float* __restrict__ bias,
             const float* __restrict__ resid,
             int M, int N, int K,
             long long sA, long long sB, long long sC, float scale)
{
  __shared__ __align__(16) short ldsA[128 * 64];
  __shared__ __align__(16) short ldsB[128 * 64];
  const int tid  = threadIdx.x;
  const int lane = tid & 63;
  const int wv   = tid >> 6;
  const int bm = blockIdx.y * 128;
  const int bn = blockIdx.x * 128;
  const long long zoA = (long long)blockIdx.z * sA;
  const long long zoB = (long long)blockIdx.z * sB;
  const long long zoC = (long long)blockIdx.z * sC;
  const int wm = (wv >> 1) << 6;
  const int wn = (wv & 1) << 6;

  f32x4 zero4 = {0.f, 0.f, 0.f, 0.f};
  f32x4 acc[4][4];
#pragma unroll
  for (int i = 0; i < 4; ++i)
#pragma unroll
    for (int j = 0; j < 4; ++j)
      acc[i][j] = zero4;

  const int s_row = wv * 8 + (lane >> 3);
  const int s_kc  = (lane & 7) ^ (s_row & 7);
  const int sm  = tid >> 3;
  const int skc = tid & 7;

  for (int k0 = 0; k0 < K; k0 += 64) {
#pragma unroll
    for (int r = 0; r < 4; ++r) {
      const int m = r * 32 + s_row;
      async_copy16((const short*)Bv + zoB + (size_t)(bn + m) * K + k0 + s_kc * 8,
                   &ldsB[m >> 3 << 9]);
    }
    if constexpr (MODE == 0) {
#pragma unroll
      for (int r = 0; r < 4; ++r) {
        const int m = r * 32 + sm;
        const float* ap = (const float*)Av + zoA + (size_t)(bm + m) * K + k0 + skc * 8;
        float4 f0 = *(const float4*)ap;
        float4 f1 = *(const float4*)(ap + 4);
        short8 av;
        av[0] = f2b(f0.x); av[1] = f2b(f0.y); av[2] = f2b(f0.z); av[3] = f2b(f0.w);
        av[4] = f2b(f1.x); av[5] = f2b(f1.y); av[6] = f2b(f1.z); av[7] = f2b(f1.w);
        *(short8*)&ldsA[((m << 3) + (skc ^ (m & 7))) << 3] = av;
      }
    } else {
#pragma unroll
      for (int r = 0; r < 4; ++r) {
        const int m = r * 32 + s_row;
        async_copy16((const short*)Av + zoA + (size_t)(bm + m) * K + k0 + s_kc * 8,
                     &ldsA[m >> 3 << 9]);
      }
    }
    __syncthreads();
#pragma unroll
    for (int kk = 0; kk < 2; ++kk) {
      const int kcr = (kk << 2) + (lane >> 4);
      short8 af[4], bfv[4];
#pragma unroll
      for (int i = 0; i < 4; ++i) {
        const int ma = wm + i * 16 + (lane & 15);
        const int nb = wn + i * 16 + (lane & 15);
        af[i]  = *(const short8*)&ldsA[((ma << 3) + (kcr ^ (ma & 7))) << 3];
        bfv[i] = *(const short8*)&ldsB[((nb << 3) + (kcr ^ (nb & 7))) << 3];
      }
#pragma unroll
      for (int i = 0; i < 4; ++i)
#pragma unroll
        for (int j = 0; j < 4; ++j)
          acc[i][j] = __builtin_amdgcn_mfma_f32_16x16x32_bf16(af[i], bfv[j], acc[i][j], 0, 0, 0);
    }
    __syncthreads();
  }

  // C/D layout: col = lane&15, row = (lane>>4)*4 + reg  [measured m89/m91]
#pragma unroll
  for (int i = 0; i < 4; ++i) {
    const int row0 = bm + wm + i * 16 + ((lane >> 4) << 2);
#pragma unroll
    for (int j = 0; j < 4; ++j) {
      const int n = bn + wn + j * 16 + (lane & 15);
      float badd = 0.f;
      if (MODE == 0 || MODE == 3) badd = bias[n];
#pragma unroll
      for (int r = 0; r < 4; ++r) {
        float val = acc[i][j][r];
        if (MODE == 0) val += badd;
        if constexpr (MODE == 3) {
          val += badd + resid[zoC + (size_t)(row0 + r) * N + n];
          ((float*)Cv)[zoC + (size_t)(row0 + r) * N + n] = val;
        } else {
          ((short*)Cv)[zoC + (size_t)(row0 + r) * N + n] = f2b(val);
        }
      }
    }
  }
  (void)scale;
}

// ---------------------------------------------------------------------------
// Fused flash attention, one direction per z-slice.
// Block: 256 thr (4 waves), Q-tile 64 rows. j-loop over 16 KV tiles of 128.
//   S phase : S(64x128) = Qa_tile @ Qb_j^T, waves split cols (32 each).
//   softmax : online (m,l,alpha) per row; m/l in regs (C-layout rows identical
//             for S-acc and O-acc); cross-wave stats via LDS st[64][8].
//   P       : exp(S-m) bf16 -> LDS in A-fragment layout (chunk swizzle
//             kc^(row&15)).
//   PV phase: wave w owns O cols [128w,128w+128); stages its private VT chunk
//             (128 d x 32 s) async with wave-local s_waitcnt; K=32 MFMAs.
// LDS pool 50KB: qa[0,8K) qb[8K,24K) | vt[0,32K) (aliased) | P[32K,48K) |
// stats[48K,50K).
// ---------------------------------------------------------------------------
__global__ __launch_bounds__(256, 2)
void flash_attn(const short* __restrict__ Ql, const short* __restrict__ Qr,
                const short* __restrict__ VTl, const short* __restrict__ VTr,
                short* __restrict__ Fl, short* __restrict__ Fr, float scale)
{
  __shared__ __align__(16) char pool[51200];
  short* qa = (short*)pool;             // S phase
  short* qb = (short*)(pool + 8192);    // S phase
  short* vt = (short*)pool;             // PV phase (aliases qa/qb)
  short* pP = (short*)(pool + 32768);   // P tile 64x128 bf16
  float* st = (float*)(pool + 49152);   // [row][0..3]=max parts, [4..7]=sum parts

  const int tid = threadIdx.x, lane = tid & 63, wv = tid >> 6;
  const int q = lane >> 4, c = lane & 15;
  const int qt  = blockIdx.x;                    // 0..31
  const int dir = blockIdx.y >> 3, b = blockIdx.y & 7;
  const short* Qa = (dir ? Qr : Ql) + (size_t)b * Tt * Cc;
  const short* Qb = (dir ? Ql : Qr) + (size_t)b * Tt * Cc;
  const short* Vt = (dir ? VTl : VTr) + (size_t)b * Cc * Tt;
  short* Fo       = (dir ? Fr : Fl) + (size_t)b * Tt * Cc;

  f32x4 zero4 = {0.f, 0.f, 0.f, 0.f};
  f32x4 accO[4][8];
#pragma unroll
  for (int i = 0; i < 4; ++i)
#pragma unroll
    for (int jd = 0; jd < 8; ++jd)
      accO[i][jd] = zero4;
  float mrow[4][4], lrow[4][4];
#pragma unroll
  for (int i = 0; i < 4; ++i)
#pragma unroll
    for (int r = 0; r < 4; ++r) { mrow[i][r] = -1e30f; lrow[i][r] = 0.f; }

  const int sl_r = lane >> 3;   // staging: row-in-8
  const int sl_k = lane & 7;

#pragma unroll 1
  for (int j = 0; j < 16; ++j) {
    __syncthreads();   // prev PV reads done before overwriting qa/qb region
    f32x4 accS[4][2];
#pragma unroll
    for (int i = 0; i < 4; ++i) { accS[i][0] = zero4; accS[i][1] = zero4; }

    // ---- S = Qa_tile @ Qb_j^T ----
    for (int k0 = 0; k0 < Cc; k0 += 64) {
#pragma unroll
      for (int r = 0; r < 2; ++r) {
        const int m = r * 32 + wv * 8 + sl_r;
        const int kc = sl_k ^ (m & 7);
        async_copy16(Qa + (size_t)(qt * 64 + m) * Cc + k0 + kc * 8, &qa[m >> 3 << 9]);
      }
#pragma unroll
      for (int r = 0; r < 4; ++r) {
        const int m = r * 32 + wv * 8 + sl_r;
        const int kc = sl_k ^ (m & 7);
        async_copy16(Qb + (size_t)(j * 128 + m) * Cc + k0 + kc * 8, &qb[m >> 3 << 9]);
      }
      __syncthreads();
#pragma unroll
      for (int kk = 0; kk < 2; ++kk) {
        const int kcr = (kk << 2) + q;
        short8 af[4], bf[2];
#pragma unroll
        for (int i = 0; i < 4; ++i) {
          const int ma = 16 * i + c;
          af[i] = *(const short8*)&qa[((ma << 3) + (kcr ^ (ma & 7))) << 3];
        }
#pragma unroll
        for (int n = 0; n < 2; ++n) {
          const int nb = 32 * wv + 16 * n + c;
          bf[n] = *(const short8*)&qb[((nb << 3) + (kcr ^ (nb & 7))) << 3];
        }
#pragma unroll
        for (int i = 0; i < 4; ++i)
#pragma unroll
          for (int n = 0; n < 2; ++n)
            accS[i][n] = __builtin_amdgcn_mfma_f32_16x16x32_bf16(af[i], bf[n], accS[i][n], 0, 0, 0);
      }
      __syncthreads();
    }

    // ---- online softmax: wave-partial row max -> LDS ----
#pragma unroll
    for (int i = 0; i < 4; ++i)
#pragma unroll
      for (int r = 0; r < 4; ++r) {
        float v = fmaxf(accS[i][0][r], accS[i][1][r]) * scale;
        v = fmaxf(v, __shfl_xor(v, 1, 64));
        v = fmaxf(v, __shfl_xor(v, 2, 64));
        v = fmaxf(v, __shfl_xor(v, 4, 64));
        v = fmaxf(v, __shfl_xor(v, 8, 64));
        if (c == 0) st[(16 * i + 4 * q + r) * 8 + wv] = v;
      }
    __syncthreads();

    float psum[4][4];
#pragma unroll
    for (int i = 0; i < 4; ++i)
#pragma unroll
      for (int r = 0; r < 4; ++r) {
        const int row = 16 * i + 4 * q + r;
        const float4 m4 = *(const float4*)&st[row * 8];
        const float mt = fmaxf(fmaxf(m4.x, m4.y), fmaxf(m4.z, m4.w));
        const float mn = fmaxf(mrow[i][r], mt);
        const float al = __expf(mrow[i][r] - mn);
        mrow[i][r] = mn;
        lrow[i][r] *= al;
#pragma unroll
        for (int jd = 0; jd < 8; ++jd) accO[i][jd] *= al;
        const float p0 = __expf(accS[i][0][r] * scale - mn);
        const float p1 = __expf(accS[i][1][r] * scale - mn);
        float ps = p0 + p1;
        ps += __shfl_xor(ps, 1, 64);
        ps += __shfl_xor(ps, 2, 64);
        ps += __shfl_xor(ps, 4, 64);
        ps += __shfl_xor(ps, 8, 64);
        psum[i][r] = ps;
        const int col0 = 32 * wv + c;
        const int col1 = col0 + 16;
        pP[((row << 4) + ((col0 >> 3) ^ (row & 15))) * 8 + (col0 & 7)] = f2b(p0);
        pP[((row << 4) + ((col1 >> 3) ^ (row & 15))) * 8 + (col1 & 7)] = f2b(p1);
      }
    if (c == 0) {
#pragma unroll
      for (int i = 0; i < 4; ++i)
#pragma unroll
        for (int r = 0; r < 4; ++r)
          st[(16 * i + 4 * q + r) * 8 + 4 + wv] = psum[i][r];
    }
    __syncthreads();   // P + sum partials visible
#pragma unroll
    for (int i = 0; i < 4; ++i)
#pragma unroll
      for (int r = 0; r < 4; ++r) {
        const float4 s4 = *(const float4*)&st[(16 * i + 4 * q + r) * 8 + 4];
        lrow[i][r] += s4.x + s4.y + s4.z + s4.w;
      }

    // ---- PV: O += P @ V_j  (wave-private VT staging, wave-local waits) ----
    short* vtw = vt + wv * 4096;   // 8KB per wave
#pragma unroll 1
    for (int cs = 0; cs < 4; ++cs) {
      __builtin_amdgcn_s_waitcnt(0);   // prior ds_reads done before restage
#pragma unroll
      for (int t = 0; t < 8; ++t) {
        const int idx = t * 64 + lane;
        const int d = idx >> 2;
        const int cc = (idx & 3) ^ (d & 3) ^ ((d >> 2) & 3);
        async_copy16(Vt + (size_t)(128 * wv + d) * Tt + j * 128 + cs * 32 + cc * 8,
                     &vtw[t << 9]);
      }
      __builtin_amdgcn_s_waitcnt(0);   // staging complete
      short8 pf[4];
#pragma unroll
      for (int i = 0; i < 4; ++i) {
        const int ma = 16 * i + c;
        pf[i] = *(const short8*)&pP[((ma << 4) + (((cs << 2) + q) ^ (ma & 15))) << 3];
      }
#pragma unroll
      for (int jd = 0; jd < 8; ++jd) {
        const int nb = 16 * jd + c;
        const short8 vf = *(const short8*)&vtw[((nb << 2) + (q ^ (nb & 3) ^ ((nb >> 2) & 3))) << 3];
#pragma unroll
        for (int i = 0; i < 4; ++i)
          accO[i][jd] = __builtin_amdgcn_mfma_f32_16x16x32_bf16(pf[i], vf, accO[i][jd], 0, 0, 0);
      }
    }
  }

  // ---- epilogue: O / l -> F (bf16), C-layout ----
#pragma unroll
  for (int i = 0; i < 4; ++i)
#pragma unroll
    for (int r = 0; r < 4; ++r) {
      const int row = qt * 64 + 16 * i + 4 * q + r;
      const float inv = 1.0f / lrow[i][r];
#pragma unroll
      for (int jd = 0; jd < 8; ++jd)
        Fo[(size_t)row * Cc + 128 * wv + 16 * jd + c] = f2b(accO[i][jd][r] * inv);
    }
}

// ---------------------------------------------------------------------------
// One-shot weight/bias packing: fp32 -> bf16, proj pairs concatenated to N=1024.
// ---------------------------------------------------------------------------
__global__ __launch_bounds__(256)
void pack_all(const float* __restrict__ lw1a, const float* __restrict__ lw1b,
              const float* __restrict__ rw1a, const float* __restrict__ rw1b,
              const float* __restrict__ w3lf, const float* __restrict__ w3rf,
              const float* __restrict__ lb1a, const float* __restrict__ lb1b,
              const float* __restrict__ rb1a, const float* __restrict__ rb1b,
              short* __restrict__ Wl, short* __restrict__ Wr,
              short* __restrict__ W3l, short* __restrict__ W3r,
              float* __restrict__ BL, float* __restrict__ BR)
{
  const int i = blockIdx.x * 256 + threadIdx.x;
  if (i < 524288) {
    Wl[i] = f2b(i < 262144 ? lw1a[i] : lw1b[i - 262144]);
  } else if (i < 1048576) {
    const int j = i - 524288;
    Wr[j] = f2b(j < 262144 ? rw1a[j] : rw1b[j - 262144]);
  } else if (i < 1310720) {
    W3l[i - 1048576] = f2b(w3lf[i - 1048576]);
  } else if (i < 1572864) {
    W3r[i - 1310720] = f2b(w3rf[i - 1310720]);
  } else if (i < 1573888) {
    const int j = i - 1572864;
    BL[j] = j < 512 ? lb1a[j] : lb1b[j - 512];
  } else if (i < 1574912) {
    const int j = i - 1573888;
    BR[j] = j < 512 ? rb1a[j] : rb1b[j - 512];
  }
}

// ---------------------------------------------------------------------------
// Depthwise conv k=3 pad=1 over T. H row stride 1024, slice [colOff,colOff+512).
// ---------------------------------------------------------------------------
__global__ __launch_bounds__(256)
void dw_kernel(const short* __restrict__ H, const float* __restrict__ w2,
               const float* __restrict__ b2, short* __restrict__ out, int colOff)
{
  const int idx = blockIdx.x * 256 + threadIdx.x;
  const int c8 = idx & 63;
  const int bt = idx >> 6;
  const int t  = bt & (Tt - 1);
  const int c  = c8 << 3;
  const short* base = H + (size_t)bt * 1024 + colOff + c;
  short8 zz = {0, 0, 0, 0, 0, 0, 0, 0};
  short8 hm = zz, hp = zz;
  short8 h0 = *(const short8*)base;
  if (t > 0)      hm = *(const short8*)(base - 1024);
  if (t < Tt - 1) hp = *(const short8*)(base + 1024);
  short8 o;
#pragma unroll
  for (int j = 0; j < 8; ++j) {
    const int cj = c + j;
    float val = b2f(hm[j]) * w2[cj * 3 + 0]
              + b2f(h0[j]) * w2[cj * 3 + 1]
              + b2f(hp[j]) * w2[cj * 3 + 2]
              + b2[cj];
    o[j] = f2b(val);
  }
  *(short8*)(out + (size_t)bt * Cc + c) = o;
}

// ---------------------------------------------------------------------------
// Depthwise conv + transpose: outT[b,c,t] (bf16). H row stride 1024.
// ---------------------------------------------------------------------------
__global__ __launch_bounds__(256)
void dwt_kernel(const short* __restrict__ H, const float* __restrict__ w2,
                const float* __restrict__ b2, short* __restrict__ outT, int colOff)
{
  const int b  = blockIdx.z;
  const int c  = blockIdx.y * 64 + (threadIdx.x & 63);
  const int tb = blockIdx.x * 32 + (threadIdx.x >> 6) * 8;
  const short* base = H + ((size_t)b * Tt) * 1024 + colOff + c;
  float h[10];
#pragma unroll
  for (int i = 0; i < 10; ++i) {
    const int t = tb - 1 + i;
    h[i] = (t >= 0 && t < Tt) ? b2f(base[(size_t)t * 1024]) : 0.f;
  }
  const float w0 = w2[c * 3 + 0];
  const float w1 = w2[c * 3 + 1];
  const float wp = w2[c * 3 + 2];
  const float bb = b2[c];
  short8 o;
#pragma unroll
  for (int j = 0; j < 8; ++j)
    o[j] = f2b(h[j] * w0 + h[j + 1] * w1 + h[j + 2] * wp + bb);
  *(short8*)(outT + ((size_t)b * Cc + c) * Tt + tb) = o;
}

// ---------------------------------------------------------------------------
extern "C" void kernel_launch(void* const* d_in, const int* in_sizes, int n_in,
                              void* d_out, int out_size, void* d_ws, size_t ws_size,
                              hipStream_t stream)
{
  const float* x_l    = (const float*)d_in[0];
  const float* x_r    = (const float*)d_in[1];
  const float* lp1_w1 = (const float*)d_in[2];
  const float* lp1_b1 = (const float*)d_in[3];
  const float* lp1_w2 = (const float*)d_in[4];
  const float* lp1_b2 = (const float*)d_in[5];
  const float* rp1_w1 = (const float*)d_in[6];
  const float* rp1_b1 = (const float*)d_in[7];
  const float* rp1_w2 = (const float*)d_in[8];
  const float* rp1_b2 = (const float*)d_in[9];
  const float* lp2_w1 = (const float*)d_in[10];
  const float* lp2_b1 = (const float*)d_in[11];
  const float* lp2_w2 = (const float*)d_in[12];
  const float* lp2_b2 = (const float*)d_in[13];
  const float* rp2_w1 = (const float*)d_in[14];
  const float* rp2_b1 = (const float*)d_in[15];
  const float* rp2_w2 = (const float*)d_in[16];
  const float* rp2_b2 = (const float*)d_in[17];
  const float* lp3_w  = (const float*)d_in[18];
  const float* lp3_b  = (const float*)d_in[19];
  const float* rp3_w  = (const float*)d_in[20];
  const float* rp3_b  = (const float*)d_in[21];

  short* ws = (short*)d_ws;
  const size_t SZ = (size_t)Bb * Tt * Cc;    // 8,388,608 bf16 elems (16.78 MB)
  short* Ql  = ws;
  short* Qr  = ws + SZ;
  short* VTl = ws + 2 * SZ;
  short* VTr = ws + 3 * SZ;
  short* Fl  = ws + 4 * SZ;
  short* Fr  = ws + 5 * SZ;
  short* H   = Fl;                           // phase-1 proj out (2*SZ), aliases Fl+Fr

  const size_t W_PAIR = 524288, W_SING = 262144;
  short* Wl  = ws + 6 * SZ;
  short* Wr  = Wl + W_PAIR;
  short* W3l = Wr + W_PAIR;
  short* W3r = W3l + W_SING;
  float* BL  = (float*)(W3r + W_SING);
  float* BR  = BL + 1024;
  // total ~104 MB

  float* out_l = (float*)d_out;
  float* out_r = (float*)d_out + SZ;

  const float scale = 0.04419417382415922f;  // 512^-0.5
  const int MT = Bb * Tt;                    // 16384

  dim3 blk(256);

  // ---- phase 0: pack weights ----
  pack_all<<<6152, blk, 0, stream>>>(lp1_w1, lp2_w1, rp1_w1, rp2_w1, lp3_w, rp3_w,
                                     lp1_b1, lp2_b1, rp1_b1, rp2_b1,
                                     Wl, Wr, W3l, W3r, BL, BR);

  // ---- phase 1: fused pointwise proj (N=1024) -> depthwise convs ----
  gemm_bt<0><<<dim3(8, 128, 1), blk, 0, stream>>>(x_l, Wl, H, BL, nullptr,
                                                  MT, 1024, Cc, 0, 0, 0, 1.f);
  dw_kernel <<<4096, blk, 0, stream>>>(H, lp1_w2, lp1_b2, Ql, 0);
  dwt_kernel<<<dim3(Tt / 32, 8, Bb), blk, 0, stream>>>(H, lp2_w2, lp2_b2, VTl, 512);

  gemm_bt<0><<<dim3(8, 128, 1), blk, 0, stream>>>(x_r, Wr, H, BR, nullptr,
                                                  MT, 1024, Cc, 0, 0, 0, 1.f);
  dw_kernel <<<4096, blk, 0, stream>>>(H, rp1_w2, rp1_b2, Qr, 0);
  dwt_kernel<<<dim3(Tt / 32, 8, Bb), blk, 0, stream>>>(H, rp2_w2, rp2_b2, VTr, 512);

  // ---- phase 2: fused flash attention, both directions (overwrites H) ----
  flash_attn<<<dim3(32, 16), blk, 0, stream>>>(Ql, Qr, VTl, VTr, Fl, Fr, scale);

  // ---- phase 3: output projections + residual ----
  gemm_bt<3><<<dim3(Cc / 128, MT / 128, 1), blk, 0, stream>>>(
      Fl, W3l, out_l, lp3_b, x_l, MT, Cc, Cc, 0, 0, 0, 1.f);
  gemm_bt<3><<<dim3(Cc / 128, MT / 128, 1), blk, 0, stream>>>(
      Fr, W3r, out_r, rp3_b, x_r, MT, Cc, Cc, 0, 0, 0, 1.f);

  (void)in_sizes; (void)n_in; (void)out_size; (void)ws_size;
}